// Round 3
// baseline (45.639 us; speedup 1.0000x reference)
//
#include <hip/hip_runtime.h>

// Burgers PDE step: out = d*delta_u - adv   (memory-bound 3-pt stencil)
//   delta_u = (U[i-1] - 2U[i] + U[i+1]) / dx^2
//   adv     = max(u,0)*(U[i]-U[i-1])/dx + min(u,0)*(U[i+1]-U[i])/dx
//   d       = sigmoid(d_org) * 0.01
// U padded with Dirichlet bc: U[-1]=bc[0], U[N]=bc[1].
//
// R3: same as R2 but with clang native vector type so
//     __builtin_nontemporal_store compiles (HIP float4 is a struct).

#define INV_DX  100.0f     // 1/0.01
#define INV_DX2 10000.0f   // 1/0.01^2

typedef float floatx4 __attribute__((ext_vector_type(4)));

// Fast path: n % 4 == 0 (true for N=2^25).
__global__ __launch_bounds__(256) void burgers_vec4(
    const float* __restrict__ u,
    const float* __restrict__ bc,
    const float* __restrict__ d_org,
    float* __restrict__ out,
    int n)
{
    const int quad = blockIdx.x * blockDim.x + threadIdx.x;
    const int base = quad * 4;            // always < n on this path
    const int lane = threadIdx.x & 63;

    const float d = 0.01f / (1.0f + expf(-d_org[0]));

    const floatx4 v = *reinterpret_cast<const floatx4*>(u + base);

    // Left halo: lane i takes lane i-1's v[3]; wave-edge lane loads it.
    float left = __shfl_up(v[3], 1);
    if (lane == 0) left = (base == 0) ? bc[0] : u[base - 1];

    // Right halo: lane i takes lane i+1's v[0]; wave-edge lane loads it.
    float right = __shfl_down(v[0], 1);
    if (lane == 63) right = (base + 4 == n) ? bc[1] : u[base + 4];

    const float c[6] = {left, v[0], v[1], v[2], v[3], right};
    floatx4 o;
    #pragma unroll
    for (int j = 0; j < 4; ++j) {
        const float l = c[j], m = c[j + 1], r = c[j + 2];
        const float delta = (l - 2.0f * m + r) * INV_DX2;
        const float advl  = (m - l) * INV_DX;
        const float advr  = (r - m) * INV_DX;
        const float adv   = fmaxf(m, 0.0f) * advl + fminf(m, 0.0f) * advr;
        o[j] = d * delta - adv;
    }
    __builtin_nontemporal_store(o, reinterpret_cast<floatx4*>(out + base));
}

// Generic scalar fallback (any n); not used for N=2^25.
__global__ __launch_bounds__(256) void burgers_scalar(
    const float* __restrict__ u,
    const float* __restrict__ bc,
    const float* __restrict__ d_org,
    float* __restrict__ out,
    int n)
{
    const int i = blockIdx.x * blockDim.x + threadIdx.x;
    if (i >= n) return;
    const float d = 0.01f / (1.0f + expf(-d_org[0]));
    const float m = u[i];
    const float l = (i == 0)     ? bc[0] : u[i - 1];
    const float r = (i == n - 1) ? bc[1] : u[i + 1];
    const float delta = (l - 2.0f * m + r) * INV_DX2;
    const float advl  = (m - l) * INV_DX;
    const float advr  = (r - m) * INV_DX;
    const float adv   = fmaxf(m, 0.0f) * advl + fminf(m, 0.0f) * advr;
    out[i] = d * delta - adv;
}

extern "C" void kernel_launch(void* const* d_in, const int* in_sizes, int n_in,
                              void* d_out, int out_size, void* d_ws, size_t ws_size,
                              hipStream_t stream) {
    const float* u     = (const float*)d_in[0];  // state [1,1,N]
    const float* bc    = (const float*)d_in[1];  // [1,1,2]
    const float* d_org = (const float*)d_in[2];  // scalar
    float* out = (float*)d_out;

    const int n = in_sizes[0];
    const int threads = 256;

    if ((n & 3) == 0) {
        const int quads = n / 4;                       // exact
        const int blocks = (quads + threads - 1) / threads;
        burgers_vec4<<<blocks, threads, 0, stream>>>(u, bc, d_org, out, n);
    } else {
        const int blocks = (n + threads - 1) / threads;
        burgers_scalar<<<blocks, threads, 0, stream>>>(u, bc, d_org, out, n);
    }
}